// Round 16
// baseline (444.120 us; speedup 1.0000x reference)
//
#include <hip/hip_runtime.h>
#include <stdint.h>

typedef __bf16 bf16;
typedef __attribute__((ext_vector_type(8))) __bf16 bf16x8;
typedef __attribute__((ext_vector_type(4))) __bf16 bf16x4;
typedef __attribute__((ext_vector_type(4))) float f32x4;

#define DEVFN static __device__ __forceinline__

DEVFN void gload16(const bf16* g, char* l) {
  __builtin_amdgcn_global_load_lds(
      (const __attribute__((address_space(1))) void*)g,
      (__attribute__((address_space(3))) void*)l, 16, 0, 0);
}
DEVFN void gload4(const float* g, char* l) {
  __builtin_amdgcn_global_load_lds(
      (const __attribute__((address_space(1))) void*)g,
      (__attribute__((address_space(3))) void*)l, 4, 0, 0);
}

DEVFN int swz(int row, int kb) { return row * 128 + (kb ^ ((row & 7) << 4)); }

#define PS 9437184LL  // partial stride per kv-split: 16 bh * 4096 q * 144 B

// ---------------- prep: fp32 -> bf16 + weight transposes --------------------
__global__ __launch_bounds__(256) void prep_kernel(
    const float* __restrict__ x, const float* __restrict__ Wq,
    const float* __restrict__ Wk, const float* __restrict__ Wv,
    const float* __restrict__ Wp, bf16* __restrict__ xb,
    bf16* __restrict__ Wt, bf16* __restrict__ Wpt) {
  const int64_t tid = blockIdx.x * 256LL + threadIdx.x;
  const int64_t stride = (int64_t)gridDim.x * 256LL;
  for (int64_t i = tid; i < (8192LL * 512) / 4; i += stride) {
    float4 v = ((const float4*)x)[i];
    bf16x4 o = {(bf16)v.x, (bf16)v.y, (bf16)v.z, (bf16)v.w};
    ((bf16x4*)xb)[i] = o;
  }
  for (int64_t i = tid; i < 1536LL * 512; i += stride) {
    int c = (int)(i >> 9), k = (int)(i & 511);
    int wsel = c >> 9, cc = c & 511;
    const float* W = wsel == 0 ? Wq : (wsel == 1 ? Wk : Wv);
    Wt[i] = (bf16)W[k * 512 + cc];
  }
  for (int64_t i = tid; i < 512LL * 512; i += stride) {
    int c = (int)(i >> 9), k = (int)(i & 511);
    Wpt[i] = (bf16)Wp[k * 512 + c];
  }
}

// ---------------- shared 128x128 bf16 GEMM mainloop (K=512, BK=64) ----------
DEVFN void gemm_main(const bf16* __restrict__ A, const bf16* __restrict__ B,
                     int rowA0, int rowB0, char* sA, char* sB, f32x4 acc[4][4],
                     int wr, int wc, int lane, int w) {
#pragma unroll
  for (int m = 0; m < 4; m++)
#pragma unroll
    for (int n = 0; n < 4; n++) acc[m][n] = (f32x4){0.f, 0.f, 0.f, 0.f};
  const int lr = lane >> 3;
  const int kswz = 8 * ((lane & 7) ^ lr);
  for (int k0 = 0; k0 < 512; k0 += 64) {
#pragma unroll
    for (int j = 0; j < 4; j++) {
      const int c = w * 4 + j;
      gload16(A + (rowA0 + c * 8 + lr) * 512 + k0 + kswz, sA + c * 1024);
      gload16(B + (rowB0 + c * 8 + lr) * 512 + k0 + kswz, sB + c * 1024);
    }
    __syncthreads();
    bf16x8 af[4][2], bfv[4][2];
#pragma unroll
    for (int m = 0; m < 4; m++)
#pragma unroll
      for (int kk = 0; kk < 2; kk++) {
        af[m][kk] = *(const bf16x8*)(sA + swz(wr * 64 + m * 16 + (lane & 15),
                                              kk * 64 + (lane >> 4) * 16));
        bfv[m][kk] = *(const bf16x8*)(sB + swz(wc * 64 + m * 16 + (lane & 15),
                                               kk * 64 + (lane >> 4) * 16));
      }
#pragma unroll
    for (int m = 0; m < 4; m++)
#pragma unroll
      for (int n = 0; n < 4; n++)
#pragma unroll
        for (int kk = 0; kk < 2; kk++)
          acc[m][n] = __builtin_amdgcn_mfma_f32_16x16x32_bf16(
              af[m][kk], bfv[n][kk], acc[m][n], 0, 0, 0);
    __syncthreads();
  }
}

// ---------------- QKV projection ------------------------------------------
// Q is pre-scaled by 0.125*log2(e) so attention folds the softmax scale.
__global__ __launch_bounds__(256) void qkv_gemm(
    const bf16* __restrict__ xb, const bf16* __restrict__ Wt,
    const float* __restrict__ bq, const float* __restrict__ bk,
    const float* __restrict__ bv, bf16* __restrict__ Qb, bf16* __restrict__ Kb,
    bf16* __restrict__ Vt) {
  __shared__ __align__(128) char sA[16384];
  __shared__ __align__(128) char sB[16384];
  const int lane = threadIdx.x & 63, w = threadIdx.x >> 6;
  const int wr = w >> 1, wc = w & 1;
  const int rowA0 = blockIdx.y * 128;
  const int colB0 = blockIdx.x * 128;
  f32x4 acc[4][4];
  gemm_main(xb, Wt, rowA0, colB0, sA, sB, acc, wr, wc, lane, w);
  const int which = colB0 >> 9;
  const int cc0 = colB0 & 511;
  const float* bias = which == 0 ? bq : (which == 1 ? bk : bv);
  const float QSCALE = 0.18033688011112042f;  // 0.125 * log2(e)
#pragma unroll
  for (int m = 0; m < 4; m++)
#pragma unroll
    for (int n = 0; n < 4; n++)
#pragma unroll
      for (int r = 0; r < 4; r++) {
        int row = rowA0 + wr * 64 + m * 16 + (lane >> 4) * 4 + r;
        int col = cc0 + wc * 64 + n * 16 + (lane & 15);
        float v = acc[m][n][r] + bias[col];
        if (which == 0) {
          Qb[(int64_t)row * 512 + col] = (bf16)(v * QSCALE);
        } else if (which == 1) {
          Kb[(int64_t)row * 512 + col] = (bf16)v;
        } else {
          int b = row >> 12, nn = row & 4095;
          int hh = col >> 6, e = col & 63;
          Vt[(((int64_t)(b * 8 + hh)) * 64 + e) * 4096 + nn] = (bf16)v;
        }
      }
}

// ---------------- output projection (fp32 out) ----------------------------
__global__ __launch_bounds__(256) void out_gemm(const bf16* __restrict__ Ob,
                                                const bf16* __restrict__ Wpt,
                                                const float* __restrict__ bp,
                                                float* __restrict__ out) {
  __shared__ __align__(128) char sA[16384];
  __shared__ __align__(128) char sB[16384];
  const int lane = threadIdx.x & 63, w = threadIdx.x >> 6;
  const int wr = w >> 1, wc = w & 1;
  const int rowA0 = blockIdx.y * 128;
  const int colB0 = blockIdx.x * 128;
  f32x4 acc[4][4];
  gemm_main(Ob, Wpt, rowA0, colB0, sA, sB, acc, wr, wc, lane, w);
#pragma unroll
  for (int m = 0; m < 4; m++)
#pragma unroll
    for (int n = 0; n < 4; n++)
#pragma unroll
      for (int r = 0; r < 4; r++) {
        int row = rowA0 + wr * 64 + m * 16 + (lane >> 4) * 4 + r;
        int col = colB0 + wc * 64 + n * 16 + (lane & 15);
        out[(int64_t)row * 512 + col] = acc[m][n][r] + bp[col];
      }
}

// ---------------- fused flash attention: KVBLK=64, permuted-K, no P-LDS ----
// Block = 1 head, 8 waves = 8 q-subwaves (16 q each, q-tile 128), half the
// kv range (2048 = 32 tiles of KVBLK=64). Grid 1024 = 4 blocks/CU (LDS
// 33.8K). K rows staged pi-permuted so P stays in registers (r14). This
// round: manual 2x loop unroll with COMPILE-TIME buffer index (all LDS
// addresses loop-invariant) + launch_bounds(512,8) = explicit 64-VGPR
// budget so the allocator can hoist them. P packing via plain bf16 casts
// (round-15's v_cvt_pk asm was the correctness bug -> removed).
__global__ __launch_bounds__(512, 8) void attn_kernel(
    const bf16* __restrict__ Qb, const bf16* __restrict__ Kb,
    const bf16* __restrict__ Vt, const float* __restrict__ coords,
    const float* __restrict__ slopes, char* __restrict__ part) {
  __shared__ __align__(128) char sK[2 * 8192];  // [buf][64 kv][128B] swz
  __shared__ __align__(128) char sV[2 * 8192];  // [buf][64 e][128B] swz
  __shared__ __align__(128) char sC[2 * 512];   // [buf][64 kv float2]

  const int tid = threadIdx.x;
  const int lane = tid & 63, w = tid >> 6;
  const int c = lane & 15, g = lane >> 4;

  const int id = blockIdx.x;          // 0..1023
  const int bh = id & 15;             // bh%8 -> XCD
  const int qt = (id >> 4) & 31;
  const int ks = id >> 9;             // kv half
  const int b = bh >> 3, h = bh & 7;
  const int qw = qt * 128 + w * 16;
  const int bO = b * 4096;
  const int kvs = ks * 2048;

  const float LOG2E = 1.4426950408889634f;
  const float negsl2 = -slopes[h] * LOG2E;

  // Q fragments (B-operand of swapped QK^T): lane holds Q[q=c][hd=g*8+j]
  bf16x8 aq[2];
  {
    int64_t base = ((int64_t)(bO + qw + c)) * 512 + h * 64 + g * 8;
    aq[0] = *(const bf16x8*)(Qb + base);
    aq[1] = *(const bf16x8*)(Qb + base + 32);
  }
  const float* cbf = coords + (int64_t)bO * 2;
  float qcx, qcy;
  {
    float2 qc = ((const float2*)cbf)[qw + c];
    qcx = qc.x;
    qcy = qc.y;
  }

  bf16x8 ones;
#pragma unroll
  for (int jj = 0; jj < 8; jj++) ones[jj] = (bf16)1.0f;

  float m2 = -1e30f;
  f32x4 o[4], osum;
#pragma unroll
  for (int n = 0; n < 4; n++) o[n] = (f32x4){0.f, 0.f, 0.f, 0.f};
  osum = (f32x4){0.f, 0.f, 0.f, 0.f};

  const bf16* Kp = Kb + (int64_t)bO * 512 + h * 64;
  const bf16* Vp = Vt + (int64_t)(b * 8 + h) * 262144;

  // -------- staging: 1 K-granule + 1 V-granule per wave (+coords on w2/w3)
  const int gi = w * 64 + lane;
  const int kr = gi >> 3, kj = gi & 7;
  const int pkr = ((kr >> 4) & 1) * 32 + ((kr >> 2) & 3) * 8 +
                  ((kr >> 5) & 1) * 4 + (kr & 3);  // pi(kr)
  const bf16* kq = Kp + (int64_t)(kvs + pkr) * 512 + ((kj ^ (kr & 7)) * 8);
  const bf16* vq = Vp + kr * 4096 + kvs + ((kj ^ (kr & 7)) * 8);
  const float* cq = cbf + kvs * 2 + (w & 1) * 64 + lane;  // w2,w3 only

  auto STAGE = [&](int bb) {
    gload16(kq, sK + bb * 8192 + gi * 16);
    kq += 64 * 512;
    gload16(vq, sV + bb * 8192 + gi * 16);
    vq += 64;
    if (w == 2 || w == 3) {
      gload4(cq, sC + bb * 512 + (w & 1) * 256);
      cq += 128;
    }
  };

  STAGE(0);
  __syncthreads();

  const int cm = c & 7;

  // one iteration body; BB is a compile-time literal so every LDS address
  // is a loop-invariant register (+ immediate offset)
#define ITER(BB, DOSTAGE)                                                     \
  {                                                                           \
    if (DOSTAGE) STAGE(BB ^ 1);                                               \
    const char* kb = sK + (BB)*8192;                                          \
    const char* vb = sV + (BB)*8192;                                          \
    const char* cb0 = sC + (BB)*512;                                          \
    bf16x8 kf[4][2];                                                          \
    _Pragma("unroll") for (int t = 0; t < 4; t++) _Pragma("unroll") for (     \
        int kk = 0; kk < 2; kk++) kf[t][kk] =                                 \
        *(const bf16x8*)(kb + (t * 16 + c) * 128 +                            \
                         (((kk * 4 + g) ^ cm) * 16));                         \
    float s[4][4];                                                            \
    __builtin_amdgcn_s_setprio(1);                                            \
    _Pragma("unroll") for (int t = 0; t < 4; t++) {                           \
      f32x4 sa = (f32x4){0.f, 0.f, 0.f, 0.f};                                 \
      sa = __builtin_amdgcn_mfma_f32_16x16x32_bf16(kf[t][0], aq[0], sa, 0, 0, \
                                                   0);                        \
      sa = __builtin_amdgcn_mfma_f32_16x16x32_bf16(kf[t][1], aq[1], sa, 0, 0, \
                                                   0);                        \
      _Pragma("unroll") for (int r = 0; r < 4; r++) s[t][r] = sa[r];          \
    }                                                                         \
    __builtin_amdgcn_s_setprio(0);                                            \
    _Pragma("unroll") for (int t = 0; t < 4; t++) {                           \
      const int cbo = (t & 1) * 256 + (t >> 1) * 32 + g * 64;                 \
      f32x4 ca = *(const f32x4*)(cb0 + cbo);                                  \
      f32x4 cb2 = *(const f32x4*)(cb0 + cbo + 16);                            \
      float dx, dy;                                                           \
      dx = qcx - ca[0]; dy = qcy - ca[1];                                     \
      s[t][0] = __builtin_fmaf(__builtin_amdgcn_sqrtf(dx * dx + dy * dy),     \
                               negsl2, s[t][0]);                              \
      dx = qcx - ca[2]; dy = qcy - ca[3];                                     \
      s[t][1] = __builtin_fmaf(__builtin_amdgcn_sqrtf(dx * dx + dy * dy),     \
                               negsl2, s[t][1]);                              \
      dx = qcx - cb2[0]; dy = qcy - cb2[1];                                   \
      s[t][2] = __builtin_fmaf(__builtin_amdgcn_sqrtf(dx * dx + dy * dy),     \
                               negsl2, s[t][2]);                              \
      dx = qcx - cb2[2]; dy = qcy - cb2[3];                                   \
      s[t][3] = __builtin_fmaf(__builtin_amdgcn_sqrtf(dx * dx + dy * dy),     \
                               negsl2, s[t][3]);                              \
    }                                                                         \
    float lm =                                                                \
        fmaxf(fmaxf(fmaxf(s[0][0], s[0][1]), fmaxf(s[0][2], s[0][3])),        \
              fmaxf(fmaxf(s[1][0], s[1][1]), fmaxf(s[1][2], s[1][3])));       \
    lm = fmaxf(lm,                                                            \
               fmaxf(fmaxf(fmaxf(s[2][0], s[2][1]), fmaxf(s[2][2], s[2][3])), \
                     fmaxf(fmaxf(s[3][0], s[3][1]),                           \
                           fmaxf(s[3][2], s[3][3]))));                        \
    if (__any(lm > m2 + 8.f)) {                                               \
      float lmf = fmaxf(lm, __shfl_xor(lm, 16));                              \
      lmf = fmaxf(lmf, __shfl_xor(lmf, 32));                                  \
      float nm = fmaxf(m2, lmf);                                              \
      float sc = __builtin_amdgcn_exp2f(m2 - nm);                             \
      m2 = nm;                                                                \
      float scr[4];                                                           \
      _Pragma("unroll") for (int r = 0; r < 4; r++) scr[r] =                  \
          __shfl(sc, (lane & 48) | (4 * g + r));                              \
      _Pragma("unroll") for (int n = 0; n < 4; n++)                           \
          _Pragma("unroll") for (int r = 0; r < 4; r++) o[n][r] *= scr[r];    \
      _Pragma("unroll") for (int r = 0; r < 4; r++) osum[r] *= scr[r];        \
    }                                                                         \
    bf16x8 pa0, pa1;                                                          \
    _Pragma("unroll") for (int r = 0; r < 4; r++) {                           \
      pa0[r] = (bf16)__builtin_amdgcn_exp2f(s[0][r] - m2);                    \
      pa0[4 + r] = (bf16)__builtin_amdgcn_exp2f(s[2][r] - m2);                \
      pa1[r] = (bf16)__builtin_amdgcn_exp2f(s[1][r] - m2);                    \
      pa1[4 + r] = (bf16)__builtin_amdgcn_exp2f(s[3][r] - m2);                \
    }                                                                         \
    __builtin_amdgcn_s_setprio(1);                                            \
    _Pragma("unroll") for (int n = 0; n < 4; n++) {                           \
      const int e = n * 16 + c;                                               \
      bf16x8 vf0 = *(const bf16x8*)(vb + e * 128 + ((g ^ (e & 7)) * 16));     \
      bf16x8 vf1 =                                                            \
          *(const bf16x8*)(vb + e * 128 + (((4 + g) ^ (e & 7)) * 16));        \
      o[n] = __builtin_amdgcn_mfma_f32_16x16x32_bf16(pa0, vf0, o[n], 0, 0,    \
                                                     0);                      \
      o[n] = __builtin_amdgcn_mfma_f32_16x16x32_bf16(pa1, vf1, o[n], 0, 0,    \
                                                     0);                      \
    }                                                                         \
    osum = __builtin_amdgcn_mfma_f32_16x16x32_bf16(pa0, ones, osum, 0, 0, 0); \
    osum = __builtin_amdgcn_mfma_f32_16x16x32_bf16(pa1, ones, osum, 0, 0, 0); \
    __builtin_amdgcn_s_setprio(0);                                            \
    __syncthreads();                                                          \
  }

  for (int u = 0; u < 16; ++u) {
    ITER(0, true);
    ITER(1, (u < 15));
  }
#undef ITER

  // epilogue: write partials {m2, osum, o[64] bf16} per q-row (144B rows)
  float m2r[4];
#pragma unroll
  for (int r = 0; r < 4; r++)
    m2r[r] = __shfl(m2, (lane & 48) | (4 * g + r));
  char* pb0 = part + ks * PS + ((int64_t)bh * 4096 + qw) * 144;
#pragma unroll
  for (int r = 0; r < 4; r++) {
    char* pb = pb0 + (g * 4 + r) * 144;
    if (c == 0) {
      *(float*)pb = m2r[r];
      *((float*)pb + 1) = osum[r];
    }
#pragma unroll
    for (int n = 0; n < 4; n++)
      *(bf16*)(pb + 16 + (n * 16 + c) * 2) = (bf16)o[n][r];
  }
}

// ---------------- combine: merge the 2 kv-split partials -> Ob -------------
// vectorized: 8 elements per thread (16B loads/stores)
__global__ __launch_bounds__(256) void combine_kernel(
    const char* __restrict__ part, bf16* __restrict__ Ob) {
  const int t = blockIdx.x * 256 + threadIdx.x;  // 524288 threads
  const int row = t >> 3;                        // bh*4096 + q
  const int eb = (t & 7) * 8;
  const char* p0 = part + (int64_t)row * 144;
  const char* p1 = p0 + PS;
  const float m0 = *(const float*)p0, s0 = *((const float*)p0 + 1);
  const float m1 = *(const float*)p1, s1 = *((const float*)p1 + 1);
  bf16x8 o0 = *(const bf16x8*)(p0 + 16 + eb * 2);
  bf16x8 o1 = *(const bf16x8*)(p1 + 16 + eb * 2);
  const float m = fmaxf(m0, m1);
  const float w0 = __builtin_amdgcn_exp2f(m0 - m);
  const float w1 = __builtin_amdgcn_exp2f(m1 - m);
  const float inv = 1.f / (s0 * w0 + s1 * w1);
  bf16x8 res;
#pragma unroll
  for (int j = 0; j < 8; j++)
    res[j] = (bf16)(((float)o0[j] * w0 + (float)o1[j] * w1) * inv);
  const int bh = row >> 12, q = row & 4095;
  *(bf16x8*)(Ob + ((int64_t)((bh >> 3) * 4096 + q)) * 512 + (bh & 7) * 64 +
             eb) = res;
}

// ---------------- launch ---------------------------------------------------
extern "C" void kernel_launch(void* const* d_in, const int* in_sizes, int n_in,
                              void* d_out, int out_size, void* d_ws,
                              size_t ws_size, hipStream_t stream) {
  const float* x = (const float*)d_in[0];
  const float* coords = (const float*)d_in[1];
  const float* Wq = (const float*)d_in[2];
  const float* bq = (const float*)d_in[3];
  const float* Wk = (const float*)d_in[4];
  const float* bk = (const float*)d_in[5];
  const float* Wv = (const float*)d_in[6];
  const float* bv = (const float*)d_in[7];
  const float* Wp = (const float*)d_in[8];
  const float* bp = (const float*)d_in[9];
  const float* slopes = (const float*)d_in[10];

  char* ws = (char*)d_ws;
  bf16* xb = (bf16*)(ws);
  bf16* Wt = (bf16*)(ws + 8388608);
  bf16* Wpt = (bf16*)(ws + 9961472);
  bf16* Qb = (bf16*)(ws + 10485760);
  bf16* Kb = (bf16*)(ws + 18874368);
  bf16* Vt = (bf16*)(ws + 27262976);
  bf16* Ob = (bf16*)(ws + 35651584);
  char* part = ws + 44040192;  // 2 * PS = 18,874,368 B -> ends at ~62.9 MB

  hipLaunchKernelGGL(prep_kernel, dim3(1024), dim3(256), 0, stream, x, Wq, Wk,
                     Wv, Wp, xb, Wt, Wpt);
  hipLaunchKernelGGL(qkv_gemm, dim3(12, 64), dim3(256), 0, stream, xb, Wt, bq,
                     bk, bv, Qb, Kb, Vt);
  hipLaunchKernelGGL(attn_kernel, dim3(1024), dim3(512), 0, stream, Qb, Kb,
                     Vt, coords, slopes, part);
  hipLaunchKernelGGL(combine_kernel, dim3(2048), dim3(256), 0, stream, part,
                     Ob);
  hipLaunchKernelGGL(out_gemm, dim3(4, 64), dim3(256), 0, stream, Ob, Wpt, bp,
                     (float*)d_out);
}

// Round 17
// 199.927 us; speedup vs baseline: 2.2214x; 2.2214x over previous
//
#include <hip/hip_runtime.h>
#include <stdint.h>

typedef __bf16 bf16;
typedef __attribute__((ext_vector_type(8))) __bf16 bf16x8;
typedef __attribute__((ext_vector_type(4))) __bf16 bf16x4;
typedef __attribute__((ext_vector_type(4))) float f32x4;

#define DEVFN static __device__ __forceinline__

DEVFN void gload16(const bf16* g, char* l) {
  __builtin_amdgcn_global_load_lds(
      (const __attribute__((address_space(1))) void*)g,
      (__attribute__((address_space(3))) void*)l, 16, 0, 0);
}
DEVFN void gload4(const float* g, char* l) {
  __builtin_amdgcn_global_load_lds(
      (const __attribute__((address_space(1))) void*)g,
      (__attribute__((address_space(3))) void*)l, 4, 0, 0);
}

DEVFN int swz(int row, int kb) { return row * 128 + (kb ^ ((row & 7) << 4)); }

#define PS 9437184LL  // partial stride per kv-split: 16 bh * 4096 q * 144 B

// ---------------- prep: fp32 -> bf16 + weight transposes --------------------
__global__ __launch_bounds__(256) void prep_kernel(
    const float* __restrict__ x, const float* __restrict__ Wq,
    const float* __restrict__ Wk, const float* __restrict__ Wv,
    const float* __restrict__ Wp, bf16* __restrict__ xb,
    bf16* __restrict__ Wt, bf16* __restrict__ Wpt) {
  const int64_t tid = blockIdx.x * 256LL + threadIdx.x;
  const int64_t stride = (int64_t)gridDim.x * 256LL;
  for (int64_t i = tid; i < (8192LL * 512) / 4; i += stride) {
    float4 v = ((const float4*)x)[i];
    bf16x4 o = {(bf16)v.x, (bf16)v.y, (bf16)v.z, (bf16)v.w};
    ((bf16x4*)xb)[i] = o;
  }
  for (int64_t i = tid; i < 1536LL * 512; i += stride) {
    int c = (int)(i >> 9), k = (int)(i & 511);
    int wsel = c >> 9, cc = c & 511;
    const float* W = wsel == 0 ? Wq : (wsel == 1 ? Wk : Wv);
    Wt[i] = (bf16)W[k * 512 + cc];
  }
  for (int64_t i = tid; i < 512LL * 512; i += stride) {
    int c = (int)(i >> 9), k = (int)(i & 511);
    Wpt[i] = (bf16)Wp[k * 512 + c];
  }
}

// ---------------- shared 128x128 bf16 GEMM mainloop (K=512, BK=64) ----------
DEVFN void gemm_main(const bf16* __restrict__ A, const bf16* __restrict__ B,
                     int rowA0, int rowB0, char* sA, char* sB, f32x4 acc[4][4],
                     int wr, int wc, int lane, int w) {
#pragma unroll
  for (int m = 0; m < 4; m++)
#pragma unroll
    for (int n = 0; n < 4; n++) acc[m][n] = (f32x4){0.f, 0.f, 0.f, 0.f};
  const int lr = lane >> 3;
  const int kswz = 8 * ((lane & 7) ^ lr);
  for (int k0 = 0; k0 < 512; k0 += 64) {
#pragma unroll
    for (int j = 0; j < 4; j++) {
      const int c = w * 4 + j;
      gload16(A + (rowA0 + c * 8 + lr) * 512 + k0 + kswz, sA + c * 1024);
      gload16(B + (rowB0 + c * 8 + lr) * 512 + k0 + kswz, sB + c * 1024);
    }
    __syncthreads();
    bf16x8 af[4][2], bfv[4][2];
#pragma unroll
    for (int m = 0; m < 4; m++)
#pragma unroll
      for (int kk = 0; kk < 2; kk++) {
        af[m][kk] = *(const bf16x8*)(sA + swz(wr * 64 + m * 16 + (lane & 15),
                                              kk * 64 + (lane >> 4) * 16));
        bfv[m][kk] = *(const bf16x8*)(sB + swz(wc * 64 + m * 16 + (lane & 15),
                                               kk * 64 + (lane >> 4) * 16));
      }
#pragma unroll
    for (int m = 0; m < 4; m++)
#pragma unroll
      for (int n = 0; n < 4; n++)
#pragma unroll
        for (int kk = 0; kk < 2; kk++)
          acc[m][n] = __builtin_amdgcn_mfma_f32_16x16x32_bf16(
              af[m][kk], bfv[n][kk], acc[m][n], 0, 0, 0);
    __syncthreads();
  }
}

// ---------------- QKV projection ------------------------------------------
// Q is pre-scaled by 0.125*log2(e) so attention folds the softmax scale.
__global__ __launch_bounds__(256) void qkv_gemm(
    const bf16* __restrict__ xb, const bf16* __restrict__ Wt,
    const float* __restrict__ bq, const float* __restrict__ bk,
    const float* __restrict__ bv, bf16* __restrict__ Qb, bf16* __restrict__ Kb,
    bf16* __restrict__ Vt) {
  __shared__ __align__(128) char sA[16384];
  __shared__ __align__(128) char sB[16384];
  const int lane = threadIdx.x & 63, w = threadIdx.x >> 6;
  const int wr = w >> 1, wc = w & 1;
  const int rowA0 = blockIdx.y * 128;
  const int colB0 = blockIdx.x * 128;
  f32x4 acc[4][4];
  gemm_main(xb, Wt, rowA0, colB0, sA, sB, acc, wr, wc, lane, w);
  const int which = colB0 >> 9;
  const int cc0 = colB0 & 511;
  const float* bias = which == 0 ? bq : (which == 1 ? bk : bv);
  const float QSCALE = 0.18033688011112042f;  // 0.125 * log2(e)
#pragma unroll
  for (int m = 0; m < 4; m++)
#pragma unroll
    for (int n = 0; n < 4; n++)
#pragma unroll
      for (int r = 0; r < 4; r++) {
        int row = rowA0 + wr * 64 + m * 16 + (lane >> 4) * 4 + r;
        int col = cc0 + wc * 64 + n * 16 + (lane & 15);
        float v = acc[m][n][r] + bias[col];
        if (which == 0) {
          Qb[(int64_t)row * 512 + col] = (bf16)(v * QSCALE);
        } else if (which == 1) {
          Kb[(int64_t)row * 512 + col] = (bf16)v;
        } else {
          int b = row >> 12, nn = row & 4095;
          int hh = col >> 6, e = col & 63;
          Vt[(((int64_t)(b * 8 + hh)) * 64 + e) * 4096 + nn] = (bf16)v;
        }
      }
}

// ---------------- output projection (fp32 out) ----------------------------
__global__ __launch_bounds__(256) void out_gemm(const bf16* __restrict__ Ob,
                                                const bf16* __restrict__ Wpt,
                                                const float* __restrict__ bp,
                                                float* __restrict__ out) {
  __shared__ __align__(128) char sA[16384];
  __shared__ __align__(128) char sB[16384];
  const int lane = threadIdx.x & 63, w = threadIdx.x >> 6;
  const int wr = w >> 1, wc = w & 1;
  const int rowA0 = blockIdx.y * 128;
  const int colB0 = blockIdx.x * 128;
  f32x4 acc[4][4];
  gemm_main(Ob, Wpt, rowA0, colB0, sA, sB, acc, wr, wc, lane, w);
#pragma unroll
  for (int m = 0; m < 4; m++)
#pragma unroll
    for (int n = 0; n < 4; n++)
#pragma unroll
      for (int r = 0; r < 4; r++) {
        int row = rowA0 + wr * 64 + m * 16 + (lane >> 4) * 4 + r;
        int col = colB0 + wc * 64 + n * 16 + (lane & 15);
        out[(int64_t)row * 512 + col] = acc[m][n][r] + bp[col];
      }
}

// ---------------- fused flash attention: KVBLK=64, permuted-K, no P-LDS ----
// Block = 1 head, 8 waves = 8 q-subwaves (16 q each, q-tile 128), half the
// kv range (2048 = 32 tiles of KVBLK=64). Grid 1024. K rows staged
// pi-permuted so P stays in registers (r14). Manual 2x loop unroll with
// COMPILE-TIME buffer index (all LDS addresses loop-invariant). NO
// min-waves launch_bounds clamp (r16: ",8" forced VGPR=32 -> 809MB spill).
__global__ __launch_bounds__(512) void attn_kernel(
    const bf16* __restrict__ Qb, const bf16* __restrict__ Kb,
    const bf16* __restrict__ Vt, const float* __restrict__ coords,
    const float* __restrict__ slopes, char* __restrict__ part) {
  __shared__ __align__(128) char sK[2 * 8192];  // [buf][64 kv][128B] swz
  __shared__ __align__(128) char sV[2 * 8192];  // [buf][64 e][128B] swz
  __shared__ __align__(128) char sC[2 * 512];   // [buf][64 kv float2]

  const int tid = threadIdx.x;
  const int lane = tid & 63, w = tid >> 6;
  const int c = lane & 15, g = lane >> 4;

  const int id = blockIdx.x;          // 0..1023
  const int bh = id & 15;             // bh%8 -> XCD
  const int qt = (id >> 4) & 31;
  const int ks = id >> 9;             // kv half
  const int b = bh >> 3, h = bh & 7;
  const int qw = qt * 128 + w * 16;
  const int bO = b * 4096;
  const int kvs = ks * 2048;

  const float LOG2E = 1.4426950408889634f;
  const float negsl2 = -slopes[h] * LOG2E;

  // Q fragments (B-operand of swapped QK^T): lane holds Q[q=c][hd=g*8+j]
  bf16x8 aq[2];
  {
    int64_t base = ((int64_t)(bO + qw + c)) * 512 + h * 64 + g * 8;
    aq[0] = *(const bf16x8*)(Qb + base);
    aq[1] = *(const bf16x8*)(Qb + base + 32);
  }
  const float* cbf = coords + (int64_t)bO * 2;
  float qcx, qcy;
  {
    float2 qc = ((const float2*)cbf)[qw + c];
    qcx = qc.x;
    qcy = qc.y;
  }

  bf16x8 ones;
#pragma unroll
  for (int jj = 0; jj < 8; jj++) ones[jj] = (bf16)1.0f;

  float m2 = -1e30f;
  f32x4 o[4], osum;
#pragma unroll
  for (int n = 0; n < 4; n++) o[n] = (f32x4){0.f, 0.f, 0.f, 0.f};
  osum = (f32x4){0.f, 0.f, 0.f, 0.f};

  const bf16* Kp = Kb + (int64_t)bO * 512 + h * 64;
  const bf16* Vp = Vt + (int64_t)(b * 8 + h) * 262144;

  // -------- staging: 1 K-granule + 1 V-granule per wave (+coords on w2/w3)
  const int gi = w * 64 + lane;
  const int kr = gi >> 3, kj = gi & 7;
  const int pkr = ((kr >> 4) & 1) * 32 + ((kr >> 2) & 3) * 8 +
                  ((kr >> 5) & 1) * 4 + (kr & 3);  // pi(kr)
  const bf16* kq = Kp + (int64_t)(kvs + pkr) * 512 + ((kj ^ (kr & 7)) * 8);
  const bf16* vq = Vp + kr * 4096 + kvs + ((kj ^ (kr & 7)) * 8);
  const float* cq = cbf + kvs * 2 + (w & 1) * 64 + lane;  // w2,w3 only

  auto STAGE = [&](int bb) {
    gload16(kq, sK + bb * 8192 + gi * 16);
    kq += 64 * 512;
    gload16(vq, sV + bb * 8192 + gi * 16);
    vq += 64;
    if (w == 2 || w == 3) {
      gload4(cq, sC + bb * 512 + (w & 1) * 256);
      cq += 128;
    }
  };

  STAGE(0);
  __syncthreads();

  const int cm = c & 7;

  // one iteration body; BB is a compile-time literal so every LDS address
  // is a loop-invariant register (+ immediate offset)
#define ITER(BB, DOSTAGE)                                                     \
  {                                                                           \
    if (DOSTAGE) STAGE(BB ^ 1);                                               \
    const char* kb = sK + (BB)*8192;                                          \
    const char* vb = sV + (BB)*8192;                                          \
    const char* cb0 = sC + (BB)*512;                                          \
    bf16x8 kf[4][2];                                                          \
    _Pragma("unroll") for (int t = 0; t < 4; t++) _Pragma("unroll") for (     \
        int kk = 0; kk < 2; kk++) kf[t][kk] =                                 \
        *(const bf16x8*)(kb + (t * 16 + c) * 128 +                            \
                         (((kk * 4 + g) ^ cm) * 16));                         \
    float s[4][4];                                                            \
    __builtin_amdgcn_s_setprio(1);                                            \
    _Pragma("unroll") for (int t = 0; t < 4; t++) {                           \
      f32x4 sa = (f32x4){0.f, 0.f, 0.f, 0.f};                                 \
      sa = __builtin_amdgcn_mfma_f32_16x16x32_bf16(kf[t][0], aq[0], sa, 0, 0, \
                                                   0);                        \
      sa = __builtin_amdgcn_mfma_f32_16x16x32_bf16(kf[t][1], aq[1], sa, 0, 0, \
                                                   0);                        \
      _Pragma("unroll") for (int r = 0; r < 4; r++) s[t][r] = sa[r];          \
    }                                                                         \
    __builtin_amdgcn_s_setprio(0);                                            \
    _Pragma("unroll") for (int t = 0; t < 4; t++) {                           \
      const int cbo = (t & 1) * 256 + (t >> 1) * 32 + g * 64;                 \
      f32x4 ca = *(const f32x4*)(cb0 + cbo);                                  \
      f32x4 cb2 = *(const f32x4*)(cb0 + cbo + 16);                            \
      float dx, dy;                                                           \
      dx = qcx - ca[0]; dy = qcy - ca[1];                                     \
      s[t][0] = __builtin_fmaf(__builtin_amdgcn_sqrtf(dx * dx + dy * dy),     \
                               negsl2, s[t][0]);                              \
      dx = qcx - ca[2]; dy = qcy - ca[3];                                     \
      s[t][1] = __builtin_fmaf(__builtin_amdgcn_sqrtf(dx * dx + dy * dy),     \
                               negsl2, s[t][1]);                              \
      dx = qcx - cb2[0]; dy = qcy - cb2[1];                                   \
      s[t][2] = __builtin_fmaf(__builtin_amdgcn_sqrtf(dx * dx + dy * dy),     \
                               negsl2, s[t][2]);                              \
      dx = qcx - cb2[2]; dy = qcy - cb2[3];                                   \
      s[t][3] = __builtin_fmaf(__builtin_amdgcn_sqrtf(dx * dx + dy * dy),     \
                               negsl2, s[t][3]);                              \
    }                                                                         \
    float lm =                                                                \
        fmaxf(fmaxf(fmaxf(s[0][0], s[0][1]), fmaxf(s[0][2], s[0][3])),        \
              fmaxf(fmaxf(s[1][0], s[1][1]), fmaxf(s[1][2], s[1][3])));       \
    lm = fmaxf(lm,                                                            \
               fmaxf(fmaxf(fmaxf(s[2][0], s[2][1]), fmaxf(s[2][2], s[2][3])), \
                     fmaxf(fmaxf(s[3][0], s[3][1]),                           \
                           fmaxf(s[3][2], s[3][3]))));                        \
    if (__any(lm > m2 + 8.f)) {                                               \
      float lmf = fmaxf(lm, __shfl_xor(lm, 16));                              \
      lmf = fmaxf(lmf, __shfl_xor(lmf, 32));                                  \
      float nm = fmaxf(m2, lmf);                                              \
      float sc = __builtin_amdgcn_exp2f(m2 - nm);                             \
      m2 = nm;                                                                \
      float scr[4];                                                           \
      _Pragma("unroll") for (int r = 0; r < 4; r++) scr[r] =                  \
          __shfl(sc, (lane & 48) | (4 * g + r));                              \
      _Pragma("unroll") for (int n = 0; n < 4; n++)                           \
          _Pragma("unroll") for (int r = 0; r < 4; r++) o[n][r] *= scr[r];    \
      _Pragma("unroll") for (int r = 0; r < 4; r++) osum[r] *= scr[r];        \
    }                                                                         \
    bf16x8 pa0, pa1;                                                          \
    _Pragma("unroll") for (int r = 0; r < 4; r++) {                           \
      pa0[r] = (bf16)__builtin_amdgcn_exp2f(s[0][r] - m2);                    \
      pa0[4 + r] = (bf16)__builtin_amdgcn_exp2f(s[2][r] - m2);                \
      pa1[r] = (bf16)__builtin_amdgcn_exp2f(s[1][r] - m2);                    \
      pa1[4 + r] = (bf16)__builtin_amdgcn_exp2f(s[3][r] - m2);                \
    }                                                                         \
    __builtin_amdgcn_s_setprio(1);                                            \
    _Pragma("unroll") for (int n = 0; n < 4; n++) {                           \
      const int e = n * 16 + c;                                               \
      bf16x8 vf0 = *(const bf16x8*)(vb + e * 128 + ((g ^ (e & 7)) * 16));     \
      bf16x8 vf1 =                                                            \
          *(const bf16x8*)(vb + e * 128 + (((4 + g) ^ (e & 7)) * 16));        \
      o[n] = __builtin_amdgcn_mfma_f32_16x16x32_bf16(pa0, vf0, o[n], 0, 0,    \
                                                     0);                      \
      o[n] = __builtin_amdgcn_mfma_f32_16x16x32_bf16(pa1, vf1, o[n], 0, 0,    \
                                                     0);                      \
    }                                                                         \
    osum = __builtin_amdgcn_mfma_f32_16x16x32_bf16(pa0, ones, osum, 0, 0, 0); \
    osum = __builtin_amdgcn_mfma_f32_16x16x32_bf16(pa1, ones, osum, 0, 0, 0); \
    __builtin_amdgcn_s_setprio(0);                                            \
    __syncthreads();                                                          \
  }

  for (int u = 0; u < 16; ++u) {
    ITER(0, true);
    ITER(1, (u < 15));
  }
#undef ITER

  // epilogue: write partials {m2, osum, o[64] bf16} per q-row (144B rows)
  float m2r[4];
#pragma unroll
  for (int r = 0; r < 4; r++)
    m2r[r] = __shfl(m2, (lane & 48) | (4 * g + r));
  char* pb0 = part + ks * PS + ((int64_t)bh * 4096 + qw) * 144;
#pragma unroll
  for (int r = 0; r < 4; r++) {
    char* pb = pb0 + (g * 4 + r) * 144;
    if (c == 0) {
      *(float*)pb = m2r[r];
      *((float*)pb + 1) = osum[r];
    }
#pragma unroll
    for (int n = 0; n < 4; n++)
      *(bf16*)(pb + 16 + (n * 16 + c) * 2) = (bf16)o[n][r];
  }
}

// ---------------- combine: merge the 2 kv-split partials -> Ob -------------
// vectorized: 8 elements per thread (16B loads/stores)
__global__ __launch_bounds__(256) void combine_kernel(
    const char* __restrict__ part, bf16* __restrict__ Ob) {
  const int t = blockIdx.x * 256 + threadIdx.x;  // 524288 threads
  const int row = t >> 3;                        // bh*4096 + q
  const int eb = (t & 7) * 8;
  const char* p0 = part + (int64_t)row * 144;
  const char* p1 = p0 + PS;
  const float m0 = *(const float*)p0, s0 = *((const float*)p0 + 1);
  const float m1 = *(const float*)p1, s1 = *((const float*)p1 + 1);
  bf16x8 o0 = *(const bf16x8*)(p0 + 16 + eb * 2);
  bf16x8 o1 = *(const bf16x8*)(p1 + 16 + eb * 2);
  const float m = fmaxf(m0, m1);
  const float w0 = __builtin_amdgcn_exp2f(m0 - m);
  const float w1 = __builtin_amdgcn_exp2f(m1 - m);
  const float inv = 1.f / (s0 * w0 + s1 * w1);
  bf16x8 res;
#pragma unroll
  for (int j = 0; j < 8; j++)
    res[j] = (bf16)(((float)o0[j] * w0 + (float)o1[j] * w1) * inv);
  const int bh = row >> 12, q = row & 4095;
  *(bf16x8*)(Ob + ((int64_t)((bh >> 3) * 4096 + q)) * 512 + (bh & 7) * 64 +
             eb) = res;
}

// ---------------- launch ---------------------------------------------------
extern "C" void kernel_launch(void* const* d_in, const int* in_sizes, int n_in,
                              void* d_out, int out_size, void* d_ws,
                              size_t ws_size, hipStream_t stream) {
  const float* x = (const float*)d_in[0];
  const float* coords = (const float*)d_in[1];
  const float* Wq = (const float*)d_in[2];
  const float* bq = (const float*)d_in[3];
  const float* Wk = (const float*)d_in[4];
  const float* bk = (const float*)d_in[5];
  const float* Wv = (const float*)d_in[6];
  const float* bv = (const float*)d_in[7];
  const float* Wp = (const float*)d_in[8];
  const float* bp = (const float*)d_in[9];
  const float* slopes = (const float*)d_in[10];

  char* ws = (char*)d_ws;
  bf16* xb = (bf16*)(ws);
  bf16* Wt = (bf16*)(ws + 8388608);
  bf16* Wpt = (bf16*)(ws + 9961472);
  bf16* Qb = (bf16*)(ws + 10485760);
  bf16* Kb = (bf16*)(ws + 18874368);
  bf16* Vt = (bf16*)(ws + 27262976);
  bf16* Ob = (bf16*)(ws + 35651584);
  char* part = ws + 44040192;  // 2 * PS = 18,874,368 B -> ends at ~62.9 MB

  hipLaunchKernelGGL(prep_kernel, dim3(1024), dim3(256), 0, stream, x, Wq, Wk,
                     Wv, Wp, xb, Wt, Wpt);
  hipLaunchKernelGGL(qkv_gemm, dim3(12, 64), dim3(256), 0, stream, xb, Wt, bq,
                     bk, bv, Qb, Kb, Vt);
  hipLaunchKernelGGL(attn_kernel, dim3(1024), dim3(512), 0, stream, Qb, Kb,
                     Vt, coords, slopes, part);
  hipLaunchKernelGGL(combine_kernel, dim3(2048), dim3(256), 0, stream, part,
                     Ob);
  hipLaunchKernelGGL(out_gemm, dim3(4, 64), dim3(256), 0, stream, Ob, Wpt, bp,
                     (float*)d_out);
}